// Round 5
// baseline (149.754 us; speedup 1.0000x reference)
//
#include <hip/hip_runtime.h>
#include <hip/hip_bf16.h>

// Problem constants (fixed by reference setup: N=4096, D=512, C=100)
#define D_DIM 512
#define KSTEPS 16          // 512 / 32 (K per MFMA)
#define BM 64              // row-indices per block (shared by p2i AND i2i)
#define BN 32              // columns per LDS tile (double-buffered)
#define GRIDY 8            // column chunks -> 64*8 = 512 blocks = 2/CU

typedef __bf16 bf16x8 __attribute__((ext_vector_type(8)));
typedef float  f32x4  __attribute__((ext_vector_type(4)));

__device__ __forceinline__ unsigned short f2bf_rne(float x) {
    unsigned int u = __float_as_uint(x);
    u += 0x7FFFu + ((u >> 16) & 1u);
    return (unsigned short)(u >> 16);
}

// async global->LDS, 16B per lane. Dest is wave-uniform base + lane*16 (HW rule).
__device__ __forceinline__ void g2l16(const void* g, void* l) {
    __builtin_amdgcn_global_load_lds(
        (const __attribute__((address_space(1))) unsigned int*)g,
        (__attribute__((address_space(3))) unsigned int*)l, 16, 0, 0);
}

__device__ __forceinline__ unsigned lds_addr(const void* p) {
    return (unsigned)(uintptr_t)(const __attribute__((address_space(3))) void*)p;
}

// One compute phase: 8 asm ds_read_b128 (addresses = precomputed base + imm
// offset), counted lgkm wait, sched_barrier (rule #18), setprio'd 16-MFMA
// cluster. P is compile-time so the ds offset immediates fold.
template <int P>
__device__ __forceinline__ void phase_mfma(
    const unsigned (&ad)[2][2],
    const bf16x8 (&Ap)[KSTEPS], const bf16x8 (&Ai)[KSTEPS],
    f32x4 (&aP)[2], f32x4 (&aI)[2])
{
    bf16x8 b00, b01, b10, b11, b20, b21, b30, b31;  // [k4][cg]
    asm volatile("ds_read_b128 %0, %1 offset:%2" : "=v"(b00) : "v"(ad[0][0]), "i"(P * 256));
    asm volatile("ds_read_b128 %0, %1 offset:%2" : "=v"(b01) : "v"(ad[1][0]), "i"(P * 256));
    asm volatile("ds_read_b128 %0, %1 offset:%2" : "=v"(b10) : "v"(ad[0][1]), "i"(P * 256));
    asm volatile("ds_read_b128 %0, %1 offset:%2" : "=v"(b11) : "v"(ad[1][1]), "i"(P * 256));
    asm volatile("ds_read_b128 %0, %1 offset:%2" : "=v"(b20) : "v"(ad[0][0]), "i"(P * 256 + 128));
    asm volatile("ds_read_b128 %0, %1 offset:%2" : "=v"(b21) : "v"(ad[1][0]), "i"(P * 256 + 128));
    asm volatile("ds_read_b128 %0, %1 offset:%2" : "=v"(b30) : "v"(ad[0][1]), "i"(P * 256 + 128));
    asm volatile("ds_read_b128 %0, %1 offset:%2" : "=v"(b31) : "v"(ad[1][1]), "i"(P * 256 + 128));
    asm volatile("s_waitcnt lgkmcnt(0)" ::: "memory");
    __builtin_amdgcn_sched_barrier(0);
    __builtin_amdgcn_s_setprio(1);
    aP[0] = __builtin_amdgcn_mfma_f32_16x16x32_bf16(Ap[P*4+0], b00, aP[0], 0, 0, 0);
    aI[0] = __builtin_amdgcn_mfma_f32_16x16x32_bf16(Ai[P*4+0], b00, aI[0], 0, 0, 0);
    aP[1] = __builtin_amdgcn_mfma_f32_16x16x32_bf16(Ap[P*4+0], b01, aP[1], 0, 0, 0);
    aI[1] = __builtin_amdgcn_mfma_f32_16x16x32_bf16(Ai[P*4+0], b01, aI[1], 0, 0, 0);
    aP[0] = __builtin_amdgcn_mfma_f32_16x16x32_bf16(Ap[P*4+1], b10, aP[0], 0, 0, 0);
    aI[0] = __builtin_amdgcn_mfma_f32_16x16x32_bf16(Ai[P*4+1], b10, aI[0], 0, 0, 0);
    aP[1] = __builtin_amdgcn_mfma_f32_16x16x32_bf16(Ap[P*4+1], b11, aP[1], 0, 0, 0);
    aI[1] = __builtin_amdgcn_mfma_f32_16x16x32_bf16(Ai[P*4+1], b11, aI[1], 0, 0, 0);
    aP[0] = __builtin_amdgcn_mfma_f32_16x16x32_bf16(Ap[P*4+2], b20, aP[0], 0, 0, 0);
    aI[0] = __builtin_amdgcn_mfma_f32_16x16x32_bf16(Ai[P*4+2], b20, aI[0], 0, 0, 0);
    aP[1] = __builtin_amdgcn_mfma_f32_16x16x32_bf16(Ap[P*4+2], b21, aP[1], 0, 0, 0);
    aI[1] = __builtin_amdgcn_mfma_f32_16x16x32_bf16(Ai[P*4+2], b21, aI[1], 0, 0, 0);
    aP[0] = __builtin_amdgcn_mfma_f32_16x16x32_bf16(Ap[P*4+3], b30, aP[0], 0, 0, 0);
    aI[0] = __builtin_amdgcn_mfma_f32_16x16x32_bf16(Ai[P*4+3], b30, aI[0], 0, 0, 0);
    aP[1] = __builtin_amdgcn_mfma_f32_16x16x32_bf16(Ap[P*4+3], b31, aP[1], 0, 0, 0);
    aI[1] = __builtin_amdgcn_mfma_f32_16x16x32_bf16(Ai[P*4+3], b31, aI[1], 0, 0, 0);
    __builtin_amdgcn_s_setprio(0);
}

// 512 blocks x 256 threads; each wave normalizes 4 rows (lane-parallel over D).
// Also zeroes the nd accumulator (blocks 0..15), replacing the memset dispatch.
__global__ __launch_bounds__(256) void normalize_rows(
    const float* __restrict__ inst, const float* __restrict__ proxy,
    unsigned short* __restrict__ instb, unsigned short* __restrict__ proxyb,
    float* __restrict__ nd, int N)
{
    const int lane = threadIdx.x & 63;
    const int wave = threadIdx.x >> 6;
    const int base = blockIdx.x * 16 + wave * 4;
    #pragma unroll
    for (int i = 0; i < 4; ++i) {
        const int row = base + i;
        const float* src;
        unsigned short* dst;
        if (row < N) { src = inst  + (size_t)row * D_DIM;        dst = instb  + (size_t)row * D_DIM; }
        else         { src = proxy + (size_t)(row - N) * D_DIM;  dst = proxyb + (size_t)(row - N) * D_DIM; }
        float4 v0 = ((const float4*)src)[lane * 2];
        float4 v1 = ((const float4*)src)[lane * 2 + 1];
        float ss = v0.x*v0.x + v0.y*v0.y + v0.z*v0.z + v0.w*v0.w
                 + v1.x*v1.x + v1.y*v1.y + v1.z*v1.z + v1.w*v1.w;
        #pragma unroll
        for (int off = 32; off > 0; off >>= 1) ss += __shfl_xor(ss, off, 64);
        const float inv = 1.0f / fmaxf(sqrtf(ss), 1e-8f);
        ushort4 o0, o1;
        o0.x = f2bf_rne(v0.x * inv); o0.y = f2bf_rne(v0.y * inv);
        o0.z = f2bf_rne(v0.z * inv); o0.w = f2bf_rne(v0.w * inv);
        o1.x = f2bf_rne(v1.x * inv); o1.y = f2bf_rne(v1.y * inv);
        o1.z = f2bf_rne(v1.z * inv); o1.w = f2bf_rne(v1.w * inv);
        ((ushort4*)dst)[lane * 2]     = o0;
        ((ushort4*)dst)[lane * 2 + 1] = o1;
    }
    if (blockIdx.x < 16)
        ((float4*)nd)[blockIdx.x * 256 + threadIdx.x] = make_float4(0.f, 0.f, 0.f, 0.f);
}

// Counted-vmcnt phase-interleaved schedule (T3+T4+T5), r2 shape.
// Per tile: 4 phases x {stage 2 async loads of t+1, raw s_barrier, 8 asm
// ds_read_b128, lgkmcnt(0)+sched_barrier, setprio'd 16-MFMA}. ONE vmcnt(2)
// per tile (phase 0) keeps next-tile loads in flight across barriers; one
// end-of-tile barrier closes the WAR race on the freed buffer.
// nd layout: [p2i_num | p2i_den | i2i_num | i2i_den], each N floats, pre-zeroed.
__global__ __launch_bounds__(256, 2) void fused_scores(
    const unsigned short* __restrict__ instb,
    const unsigned short* __restrict__ proxyb,
    const float* __restrict__ negmask,   // [C, N]
    const int*  __restrict__ labels,     // [N]
    const float* __restrict__ temp_p,
    const float* __restrict__ margin_p,
    float* __restrict__ nd,
    int N, int colsPerBlock)
{
    __shared__ unsigned short Bt0[BN * D_DIM];   // 32 KB
    __shared__ unsigned short Bt1[BN * D_DIM];   // 32 KB

    const int tid  = threadIdx.x;
    const int lane = tid & 63;
    const int wave = tid >> 6;      // 0..3
    const int quad = lane >> 4;     // 0..3
    const int l16  = lane & 15;

    // T1: column-chunk -> XCD partition. wgid%8 == XCD (round-robin dispatch);
    // each chunk's 64 blocks = exactly 2 per CU on one XCD -> B panel L2-local.
    const int bx = blockIdx.x >> 3;
    const int by = blockIdx.x & 7;

    const int row0   = bx * BM + wave * 16;      // wave's 16 row-indices
    const int j0base = by * colsPerBlock;

    const float temp  = *temp_p;
    const float scale = 1.44269504088896340736f / temp;   // log2(e)/t
    const float bias  = -(*margin_p) * scale;

    // Two A slabs resident in registers: MFMA A-layout A[m=lane&15][k=quad*8+j]
    bf16x8 Ap[KSTEPS], Ai[KSTEPS];
    {
        const unsigned short* pr = proxyb + (size_t)(row0 + l16) * D_DIM + quad * 8;
        const unsigned short* ir = instb  + (size_t)(row0 + l16) * D_DIM + quad * 8;
        #pragma unroll
        for (int ks = 0; ks < KSTEPS; ks++) {
            Ap[ks] = *(const bf16x8*)(pr + ks * 32);
            Ai[ks] = *(const bf16x8*)(ir + ks * 32);
        }
    }

    // labels for this lane's 4 output rows (C/D layout: row = quad*4 + r)
    int lab[4];
    #pragma unroll
    for (int r = 0; r < 4; r++) lab[r] = labels[row0 + quad * 4 + r];

    float numP[4] = {0.f,0.f,0.f,0.f}, denP[4] = {0.f,0.f,0.f,0.f};
    float numI[4] = {0.f,0.f,0.f,0.f}, denI[4] = {0.f,0.f,0.f,0.f};

    // Tile-invariant per-lane LDS read offsets (bytes). Read addr for (ks,cg):
    // rB*1024 + chs*16, chs = (ks*4+quad)^(l16&7); split as base[cg][e=ks&1]
    // + (ks>>1)*128 immediate.
    const int r3 = l16 & 7;
    unsigned off_[2][2];
    #pragma unroll
    for (int cg = 0; cg < 2; ++cg)
        #pragma unroll
        for (int e = 0; e < 2; ++e)
            off_[cg][e] = (unsigned)((cg * 16 + l16) * (D_DIM * 2)
                        + ((((e << 2) ^ (r3 & 4)) | (quad ^ (r3 & 3))) * 16));

    const int nt = colsPerBlock / BN;            // 16 (even)

    // Stage pair q (2 of 8 row-loads) of the tile whose first column is jsrc.
    auto stage_pair = [&](unsigned short* B, int jsrc, int q) {
        #pragma unroll
        for (int s = 0; s < 2; ++s) {
            const int it = q * 2 + s;
            const int br = it * 4 + wave;        // wave-uniform row in tile
            const unsigned short* src =
                instb + (size_t)(jsrc + br) * D_DIM + ((lane ^ (br & 7)) * 8);
            g2l16(src, B + (size_t)br * D_DIM);
        }
    };

    auto do_tile = [&](const unsigned short* curB, unsigned short* nxtB, int j0) {
        unsigned ad[2][2];
        const unsigned cb = lds_addr(curB);
        #pragma unroll
        for (int cg = 0; cg < 2; ++cg)
            #pragma unroll
            for (int e = 0; e < 2; ++e) ad[cg][e] = cb + off_[cg][e];

        // P0: issue first 2 next-tile loads, certify current buffer (vmcnt(2)
        // leaves exactly those 2 in flight), cross the barrier, compute.
        stage_pair(nxtB, j0 + BN, 0);
        asm volatile("s_waitcnt vmcnt(2)" ::: "memory");
        __builtin_amdgcn_s_barrier();

        float mk0[4], mk1[4];
        #pragma unroll
        for (int r = 0; r < 4; ++r) {
            mk0[r] = negmask[(size_t)lab[r] * N + (j0 + l16)];
            mk1[r] = negmask[(size_t)lab[r] * N + (j0 + 16 + l16)];
        }

        f32x4 aP[2] = {}, aI[2] = {};
        phase_mfma<0>(ad, Ap, Ai, aP, aI);
        stage_pair(nxtB, j0 + BN, 1);
        __builtin_amdgcn_s_barrier();
        phase_mfma<1>(ad, Ap, Ai, aP, aI);
        stage_pair(nxtB, j0 + BN, 2);
        __builtin_amdgcn_s_barrier();
        phase_mfma<2>(ad, Ap, Ai, aP, aI);
        stage_pair(nxtB, j0 + BN, 3);
        __builtin_amdgcn_s_barrier();
        phase_mfma<3>(ad, Ap, Ai, aP, aI);

        // Epilogue: compiler inserts a precise (non-draining) vmcnt for masks.
        #pragma unroll
        for (int r = 0; r < 4; ++r) {
            float zp0 = exp2f(aP[0][r] * scale + bias);
            float zi0 = exp2f(aI[0][r] * scale + bias);
            float zp1 = exp2f(aP[1][r] * scale + bias);
            float zi1 = exp2f(aI[1][r] * scale + bias);
            denP[r] += zp0 + zp1; numP[r] += zp0 * mk0[r] + zp1 * mk1[r];
            denI[r] += zi0 + zi1; numI[r] += zi0 * mk0[r] + zi1 * mk1[r];
        }

        // End-of-tile: all waves done READING curB before anyone stages into it.
        __builtin_amdgcn_s_barrier();
    };

    // Prologue: fully stage tile 0. (First do_tile's vmcnt(2) certifies it.)
    #pragma unroll
    for (int q = 0; q < 4; ++q) stage_pair(Bt0, j0base, q);

    for (int t = 0; t < nt; t += 2) {
        do_tile(Bt0, Bt1, j0base + t * BN);
        do_tile(Bt1, Bt0, j0base + (t + 1) * BN);
        // (last iteration over-stages 32 garbage rows into proxyb range — safe,
        //  in-bounds of workspace, never consumed)
    }

    // Reduce across the 16 lanes (l16) sharing each output row, then atomicAdd
    #pragma unroll
    for (int r = 0; r < 4; r++) {
        float np = numP[r], dp = denP[r], ni = numI[r], di = denI[r];
        #pragma unroll
        for (int off = 8; off > 0; off >>= 1) {
            np += __shfl_down(np, off, 16);
            dp += __shfl_down(dp, off, 16);
            ni += __shfl_down(ni, off, 16);
            di += __shfl_down(di, off, 16);
        }
        if (l16 == 0) {
            const int row = row0 + quad * 4 + r;
            atomicAdd(&nd[row],         np);
            atomicAdd(&nd[N + row],     dp);
            atomicAdd(&nd[2 * N + row], ni);
            atomicAdd(&nd[3 * N + row], di);
        }
    }
}

__global__ __launch_bounds__(1024) void loss_reduce(
    const float* __restrict__ nd, const float* __restrict__ temp_p,
    float* __restrict__ out, int N)
{
    const float t = *temp_p;
    float s = 0.f;
    for (int i = threadIdx.x; i < N; i += 1024) {
        s += (logf(nd[N + i])     - logf(nd[i]));           // p2i
        s += (logf(nd[3 * N + i]) - logf(nd[2 * N + i]));   // i2i
    }
    #pragma unroll
    for (int off = 32; off > 0; off >>= 1) s += __shfl_down(s, off, 64);
    __shared__ float wss[16];
    if ((threadIdx.x & 63) == 0) wss[threadIdx.x >> 6] = s;
    __syncthreads();
    if (threadIdx.x < 16) {
        float v = wss[threadIdx.x];
        #pragma unroll
        for (int off = 8; off > 0; off >>= 1) v += __shfl_down(v, off, 16);
        if (threadIdx.x == 0) out[0] = v / (float)N - 2.0f * logf(t);
    }
}

extern "C" void kernel_launch(void* const* d_in, const int* in_sizes, int n_in,
                              void* d_out, int out_size, void* d_ws, size_t ws_size,
                              hipStream_t stream)
{
    const float* inst     = (const float*)d_in[0];
    const float* proxy    = (const float*)d_in[1];
    const float* negmask  = (const float*)d_in[2];
    const int*   labels   = (const int*)d_in[3];
    const float* temp_p   = (const float*)d_in[4];
    const float* margin_p = (const float*)d_in[5];
    float* out = (float*)d_out;

    const int N = in_sizes[3];    // 4096 (D fixed at 512 per reference)

    unsigned short* instb  = (unsigned short*)d_ws;
    unsigned short* proxyb = instb + (size_t)N * D_DIM;
    float* nd = (float*)(proxyb + (size_t)N * D_DIM);

    normalize_rows<<<2 * N / 16, 256, 0, stream>>>(inst, proxy, instb, proxyb, nd, N);
    fused_scores<<<(N / BM) * GRIDY, 256, 0, stream>>>(instb, proxyb, negmask, labels,
                                                       temp_p, margin_p, nd, N, N / GRIDY);
    loss_reduce<<<1, 1024, 0, stream>>>(nd, temp_p, out, N);
}